// Round 8
// baseline (201.320 us; speedup 1.0000x reference)
//
#include <hip/hip_runtime.h>
#include <hip/hip_bf16.h>
#include <stdint.h>

#define BATCH 4096
#define TLEN  1024
#define MSTR  72     // LDS stride (bf16 elems) for matrices; 144B keeps 16B alignment
#define CSTR  68     // combine buffer stride (f32)

// ---- LDS layout (bytes) ----
#define OFF_ST0   0        // St_b = (T*D(e_b))^T row-major  -> fwd candidate A, b=0
#define OFF_ST1   9216     //                                   b=1
#define OFF_ZP0   18432    // Zp_b = D(e_b)*T    row-major  -> bwd candidate A, b=0
#define OFF_ZP1   27648    //                                   b=1
#define OFF_TP    36864    // bare T   plain      (bwd tail A; unused by bwd tail but uniform)
#define OFF_TT    46080    // bare T^T row-major  (fwd tail A)
#define OFF_PE    55296    // float pE[2][64]
#define OFF_PIV   55808    // float piv[64]
#define OFF_YB    56064    // u64 yball[16][16] = 2048
#define OFF_CMB   58112    // float gamma[16][CSTR] = 4352
#define OFF_LACB  62464    // float laccB[16]
#define OFF_YS    62528    // u64 ybsL[2 waves][8 words][64 lanes] = 8192
#define SMEM_SZ   70720

typedef short        bf16x4 __attribute__((ext_vector_type(4)));
typedef short        bf16x8 __attribute__((ext_vector_type(8)));
typedef float        f32x4  __attribute__((ext_vector_type(4)));
typedef unsigned int u32;
typedef unsigned int u32x4  __attribute__((ext_vector_type(4)));

#define MFMA(a,b,c) __builtin_amdgcn_mfma_f32_16x16x32_bf16(a,b,c,0,0,0)

// Hardware packed f32->2xbf16 (RNE), proven in round 7.
static __device__ __forceinline__ u32 packpair(float lo, float hi) {
    u32 r;
    asm("v_cvt_pk_bf16_f32 %0, %1, %2" : "=&v"(r) : "v"(lo), "v"(hi));
    return r;
}

// ---------------------------------------------------------------------------
// 256 wgs x 128 thr (2 waves). wg = 16-batch block, BOTH directions:
//   wave0: forward  chain  alpha_t = M_{y_t} alpha_{t-1},  M_b = D(e_b) T^T
//   wave1: backward chain  gamma_t = N_{y_t} gamma_{t+1},  N_b = D(e_b) T
// ROUND-8 DELTA: emissions are folded into TWO candidate A-matrices
// (row-scales of T — legal on the A side since A-rows = output rows shared
// by all batch columns). Per step: compute BOTH candidates (16 MFMA) and
// select per column with 16 cndmask — the 16-cndmask+16-mul EMIT is gone.
// Candidate construction = round-5-proven scaled-matrix writes; everything
// else (sigma-gather, cvt_pk pack, per-lane LDS bit-words, code-size-bounded
// loop, renorm cadence, combine) byte-identical to the passing round 7.
// ---------------------------------------------------------------------------
__global__ __launch_bounds__(128, 1) void hmm_fb(
    const int* __restrict__ y, const float* __restrict__ Tmat,
    const float* __restrict__ Emat, const float* __restrict__ Pi,
    float* __restrict__ out)
{
    __shared__ __align__(16) unsigned char SM[SMEM_SZ];

    const int tid  = threadIdx.x;
    const int wv   = tid >> 6;          // 0 = fwd, 1 = bwd
    const int lane = tid & 63;
    const int lr   = lane & 15;         // batch col
    const int g    = lane >> 4;         // k-group
    const int R0   = blockIdx.x << 4;

    float* pE  = (float*)(SM + OFF_PE);
    float* piv = (float*)(SM + OFF_PIV);
    const f32x4 zero = {0.f, 0.f, 0.f, 0.f};

    // ---- phase 0: emission + pi softmax ----
    if (tid < 64) {
        const float e0 = Emat[tid*2+0], e1 = Emat[tid*2+1];
        const float em = fmaxf(e0, e1);
        const float p0 = __expf(e0-em), p1 = __expf(e1-em);
        const float ez = 1.0f / (p0 + p1);
        pE[tid]      = p0 * ez;
        pE[64 + tid] = p1 * ez;
        float v = Pi[tid];
        float mx = v;
        #pragma unroll
        for (int d = 1; d < 64; d <<= 1) mx = fmaxf(mx, __shfl_xor(mx, d));
        const float e = __expf(v - mx);
        float z = e;
        #pragma unroll
        for (int d = 1; d < 64; d <<= 1) z += __shfl_xor(z, d);
        piv[tid] = e / z;
    }
    __syncthreads();   // phase 1 reads pE (round-5-proven ordering)

    // ---- phase 1: row-softmax of T -> candidate + bare matrices ----
    {
        const int r  = tid >> 1;          // 0..63
        const int hh = tid & 1;           // 32-col half
        float v[32];
        #pragma unroll
        for (int q = 0; q < 8; q++) {
            const float4 t4 = *(const float4*)(Tmat + r*64 + hh*32 + q*4);
            v[q*4+0]=t4.x; v[q*4+1]=t4.y; v[q*4+2]=t4.z; v[q*4+3]=t4.w;
        }
        float mx = v[0];
        #pragma unroll
        for (int k = 1; k < 32; k++) mx = fmaxf(mx, v[k]);
        mx = fmaxf(mx, __shfl_xor(mx, 1));
        float z = 0.f;
        #pragma unroll
        for (int k = 0; k < 32; k++) { v[k] = __expf(v[k]-mx); z += v[k]; }
        z += __shfl_xor(z, 1);
        const float inv = 1.0f / z;
        const float er0 = pE[r], er1 = pE[64 + r];   // row scales (bwd family)
        __hip_bfloat16* St0 = (__hip_bfloat16*)(SM + OFF_ST0);
        __hip_bfloat16* St1 = (__hip_bfloat16*)(SM + OFF_ST1);
        __hip_bfloat16* Zp0 = (__hip_bfloat16*)(SM + OFF_ZP0);
        __hip_bfloat16* Zp1 = (__hip_bfloat16*)(SM + OFF_ZP1);
        __hip_bfloat16* Tp  = (__hip_bfloat16*)(SM + OFF_TP);
        __hip_bfloat16* Tt  = (__hip_bfloat16*)(SM + OFF_TT);
        #pragma unroll
        for (int k = 0; k < 32; k++) {
            const int j = hh*32 + k;
            const float tval = v[k] * inv;
            const __hip_bfloat16 hb  = __float2bfloat16(tval);
            const __hip_bfloat16 hs0 = __float2bfloat16(tval * pE[j]);      // e0[j]*T[r][j]
            const __hip_bfloat16 hs1 = __float2bfloat16(tval * pE[64 + j]); // e1[j]*T[r][j]
            const __hip_bfloat16 hz0 = __float2bfloat16(er0 * tval);        // e0[r]*T[r][j]
            const __hip_bfloat16 hz1 = __float2bfloat16(er1 * tval);        // e1[r]*T[r][j]
            St0[j*MSTR + r] = hs0;  St1[j*MSTR + r] = hs1;   // M_b row-major
            Zp0[r*MSTR + j] = hz0;  Zp1[r*MSTR + j] = hz1;   // N_b row-major
            Tp [r*MSTR + j] = hb;   Tt [j*MSTR + r] = hb;
        }
    }
    __syncthreads();

    // ---- phase 2: gather permuted A-fragments (register-resident) ----
    // A[m][h] element j (lane g): col sigma = 32h + 4g + (j&3) + 16*(j>>2)
    bf16x8 C0[4][2], C1[4][2], TBf[4][2];
    {
        const __hip_bfloat16* B0 =
            (const __hip_bfloat16*)(SM + (wv == 0 ? OFF_ST0 : OFF_ZP0));
        const __hip_bfloat16* B1 =
            (const __hip_bfloat16*)(SM + (wv == 0 ? OFF_ST1 : OFF_ZP1));
        const __hip_bfloat16* Tb =
            (const __hip_bfloat16*)(SM + (wv == 0 ? OFF_TT : OFF_TP));
        #define LDFRAG(dst, base, m, h) { \
            const __hip_bfloat16* p_ = (base) + ((m)*16+lr)*MSTR + 32*(h) + 4*g; \
            bf16x4 lo_ = *(const bf16x4*)(p_); \
            bf16x4 hi_ = *(const bf16x4*)(p_ + 16); \
            dst[0]=lo_[0]; dst[1]=lo_[1]; dst[2]=lo_[2]; dst[3]=lo_[3]; \
            dst[4]=hi_[0]; dst[5]=hi_[1]; dst[6]=hi_[2]; dst[7]=hi_[3]; \
        }
        #pragma unroll
        for (int m = 0; m < 4; m++) {
            LDFRAG(C0[m][0],  B0, m, 0);  LDFRAG(C0[m][1],  B0, m, 1);
            LDFRAG(C1[m][0],  B1, m, 0);  LDFRAG(C1[m][1],  B1, m, 1);
            LDFRAG(TBf[m][0], Tb, m, 0);  LDFRAG(TBf[m][1], Tb, m, 1);
        }
        #undef LDFRAG
    }

    // ---- phase 3: ballot-pack y into LDS words ----
    unsigned long long* yball = (unsigned long long*)(SM + OFF_YB);
    #pragma unroll
    for (int q = 0; q < 8; q++) {
        const int row = wv*8 + q;
        const int* yr = y + (size_t)(R0 + row) * TLEN;
        #pragma unroll
        for (int w = 0; w < 16; w++) {
            const unsigned long long bal = __ballot(yr[w*64 + lane] != 0);
            if (lane == 0) yball[row*16 + w] = bal;
        }
    }
    __syncthreads();

    // ---- phase 4: per-lane bit-streams -> per-lane LDS slots ----
    // stream bit s: fwd -> y[s+1] (s=0..510); bwd -> y[1022-s]
    unsigned long long* ybsL = (unsigned long long*)(SM + OFF_YS) + wv*(8*64);
    int initbit;
    {
        unsigned long long raw[8];
        if (wv == 0) {
            #pragma unroll
            for (int w = 0; w < 8; w++) raw[w] = yball[lr*16 + w];
        } else {
            #pragma unroll
            for (int w = 0; w < 8; w++) raw[w] = __brevll(yball[lr*16 + (15-w)]);
        }
        initbit = (int)(raw[0] & 1ull);           // fwd: y[0]; bwd: y[1023]
        #pragma unroll
        for (int w = 0; w < 7; w++)
            ybsL[w*64 + lane] = (raw[w] >> 1) | (raw[w+1] << 63);
        ybsL[7*64 + lane] = raw[7] >> 1;
    }
    // Each lane reads back ONLY its own ybsL slots (same-wave write->read).

    f32x4 d0, d1, d2, d3;
    {   // init (e-vectors live only in this scope; loop no longer needs them)
        const f32x4 e0_0 = *(const f32x4*)(pE +       0 + 4*g);
        const f32x4 e0_1 = *(const f32x4*)(pE +      16 + 4*g);
        const f32x4 e0_2 = *(const f32x4*)(pE +      32 + 4*g);
        const f32x4 e0_3 = *(const f32x4*)(pE +      48 + 4*g);
        const f32x4 e1_0 = *(const f32x4*)(pE + 64 +  0 + 4*g);
        const f32x4 e1_1 = *(const f32x4*)(pE + 64 + 16 + 4*g);
        const f32x4 e1_2 = *(const f32x4*)(pE + 64 + 32 + 4*g);
        const f32x4 e1_3 = *(const f32x4*)(pE + 64 + 48 + 4*g);
        if (wv == 0) {                    // alpha_0 = piv ⊙ e_{y0}
            const f32x4 p0 = *(const f32x4*)(piv +  0 + 4*g);
            const f32x4 p1 = *(const f32x4*)(piv + 16 + 4*g);
            const f32x4 p2 = *(const f32x4*)(piv + 32 + 4*g);
            const f32x4 p3 = *(const f32x4*)(piv + 48 + 4*g);
            d0 = p0 * (initbit ? e1_0 : e0_0);
            d1 = p1 * (initbit ? e1_1 : e0_1);
            d2 = p2 * (initbit ? e1_2 : e0_2);
            d3 = p3 * (initbit ? e1_3 : e0_3);
        } else {                          // gamma_1023 = e_{y1023}
            d0 = initbit ? e1_0 : e0_0;
            d1 = initbit ? e1_1 : e0_1;
            d2 = initbit ? e1_2 : e0_2;
            d3 = initbit ? e1_3 : e0_3;
        }
    }

    // ---- main loop: 511 steps; both candidates via MFMA, per-column select ----
    f32x4 u0,u1,u2,u3, v0,v1,v2,v3;
    #define DO_MM2() { \
        u32x4 w1_, w2_; \
        w1_[0] = packpair(d0.x, d0.y);  w1_[1] = packpair(d0.z, d0.w); \
        w1_[2] = packpair(d1.x, d1.y);  w1_[3] = packpair(d1.z, d1.w); \
        w2_[0] = packpair(d2.x, d2.y);  w2_[1] = packpair(d2.z, d2.w); \
        w2_[2] = packpair(d3.x, d3.y);  w2_[3] = packpair(d3.z, d3.w); \
        const bf16x8 b1 = __builtin_bit_cast(bf16x8, w1_); \
        const bf16x8 b2 = __builtin_bit_cast(bf16x8, w2_); \
        u0 = MFMA(C0[0][0], b1, zero); u1 = MFMA(C0[1][0], b1, zero); \
        u2 = MFMA(C0[2][0], b1, zero); u3 = MFMA(C0[3][0], b1, zero); \
        v0 = MFMA(C1[0][0], b1, zero); v1 = MFMA(C1[1][0], b1, zero); \
        v2 = MFMA(C1[2][0], b1, zero); v3 = MFMA(C1[3][0], b1, zero); \
        u0 = MFMA(C0[0][1], b2, u0);   u1 = MFMA(C0[1][1], b2, u1); \
        u2 = MFMA(C0[2][1], b2, u2);   u3 = MFMA(C0[3][1], b2, u3); \
        v0 = MFMA(C1[0][1], b2, v0);   v1 = MFMA(C1[1][1], b2, v1); \
        v2 = MFMA(C1[2][1], b2, v2);   v3 = MFMA(C1[3][1], b2, v3); \
    }
    #define SELECT(cond) { \
        const bool yb_ = (cond); \
        d0 = yb_ ? v0 : u0; \
        d1 = yb_ ? v1 : u1; \
        d2 = yb_ ? v2 : u2; \
        d3 = yb_ ? v3 : u3; \
    }

    float lacc = 0.f;
    // 31 groups x 16 steps = steps 0..495; renorm at step 15 of each group.
    #pragma unroll 1
    for (int grp = 0; grp < 31; ++grp) {
        const unsigned long long cw = ybsL[((grp >> 2) << 6) + lane];
        const u32 bits = (u32)(cw >> ((grp & 3) << 4));
        #pragma unroll
        for (int i = 0; i < 16; ++i) {
            DO_MM2();
            SELECT(((bits >> i) & 1u) != 0u);
            if (i == 15) {                      // renorm every 16 steps
                float S = d0.x+d0.y+d0.z+d0.w + d1.x+d1.y+d1.z+d1.w
                        + d2.x+d2.y+d2.z+d2.w + d3.x+d3.y+d3.z+d3.w;
                S += __shfl_xor(S, 16);
                S += __shfl_xor(S, 32);
                lacc += __logf(S);
                const float rn = __builtin_amdgcn_rcpf(S);
                d0 *= rn; d1 *= rn; d2 *= rn; d3 *= rn;
            }
        }
    }
    // tail: steps 496..510 (stream bits 48..62 of word 7), rolled
    {
        u32 bits = (u32)(ybsL[(7 << 6) + lane] >> 48);
        #pragma unroll 1
        for (int i = 0; i < 15; ++i) {
            DO_MM2();
            SELECT((bits & 1u) != 0u);
            bits >>= 1;
        }
    }
    #undef DO_MM2
    #undef SELECT

    // ---- fwd: one bare matvec (no emission) -> abar_512 ----
    if (wv == 0) {
        u32x4 w1_, w2_;
        w1_[0] = packpair(d0.x, d0.y);  w1_[1] = packpair(d0.z, d0.w);
        w1_[2] = packpair(d1.x, d1.y);  w1_[3] = packpair(d1.z, d1.w);
        w2_[0] = packpair(d2.x, d2.y);  w2_[1] = packpair(d2.z, d2.w);
        w2_[2] = packpair(d3.x, d3.y);  w2_[3] = packpair(d3.z, d3.w);
        const bf16x8 b1 = __builtin_bit_cast(bf16x8, w1_);
        const bf16x8 b2 = __builtin_bit_cast(bf16x8, w2_);
        u0 = MFMA(TBf[0][0], b1, zero); u1 = MFMA(TBf[1][0], b1, zero);
        u2 = MFMA(TBf[2][0], b1, zero); u3 = MFMA(TBf[3][0], b1, zero);
        u0 = MFMA(TBf[0][1], b2, u0);   u1 = MFMA(TBf[1][1], b2, u1);
        u2 = MFMA(TBf[2][1], b2, u2);   u3 = MFMA(TBf[3][1], b2, u3);
        d0 = u0; d1 = u1; d2 = u2; d3 = u3;
    }

    // ---- combine: logP = laccF + laccB + log(abar_512 . gamma_512) ----
    if (wv == 1) {
        float* CB = (float*)(SM + OFF_CMB);
        *(f32x4*)(CB + lr*CSTR +  0 + 4*g) = d0;
        *(f32x4*)(CB + lr*CSTR + 16 + 4*g) = d1;
        *(f32x4*)(CB + lr*CSTR + 32 + 4*g) = d2;
        *(f32x4*)(CB + lr*CSTR + 48 + 4*g) = d3;
        if (lane < 16) ((float*)(SM + OFF_LACB))[lane] = lacc;
    }
    __syncthreads();
    if (wv == 0) {
        const float* CB = (const float*)(SM + OFF_CMB);
        const f32x4 q0 = *(const f32x4*)(CB + lr*CSTR +  0 + 4*g);
        const f32x4 q1 = *(const f32x4*)(CB + lr*CSTR + 16 + 4*g);
        const f32x4 q2 = *(const f32x4*)(CB + lr*CSTR + 32 + 4*g);
        const f32x4 q3 = *(const f32x4*)(CB + lr*CSTR + 48 + 4*g);
        float dot = d0.x*q0.x + d0.y*q0.y + d0.z*q0.z + d0.w*q0.w
                  + d1.x*q1.x + d1.y*q1.y + d1.z*q1.z + d1.w*q1.w
                  + d2.x*q2.x + d2.y*q2.y + d2.z*q2.z + d2.w*q2.w
                  + d3.x*q3.x + d3.y*q3.y + d3.z*q3.z + d3.w*q3.w;
        dot += __shfl_xor(dot, 16);
        dot += __shfl_xor(dot, 32);
        float lp = lacc + ((const float*)(SM + OFF_LACB))[lr] + __logf(dot);
        if (g == 0) {                      // lanes 0..15: reduce over batch
            lp += __shfl_xor(lp, 1);
            lp += __shfl_xor(lp, 2);
            lp += __shfl_xor(lp, 4);
            lp += __shfl_xor(lp, 8);
            if (lr == 0) atomicAdd(out, lp * (1.0f / BATCH));
        }
    }
}

// ---------------------------------------------------------------------------
extern "C" void kernel_launch(void* const* d_in, const int* in_sizes, int n_in,
                              void* d_out, int out_size, void* d_ws, size_t ws_size,
                              hipStream_t stream) {
    const int*   y  = (const int*)  d_in[0];
    const float* T  = (const float*)d_in[1];
    const float* E  = (const float*)d_in[2];
    const float* Pi = (const float*)d_in[3];
    float* out = (float*)d_out;
    (void)d_ws; (void)ws_size; (void)in_sizes; (void)n_in; (void)out_size;

    hipMemsetAsync(out, 0, sizeof(float), stream);
    hipLaunchKernelGGL(hmm_fb, dim3(BATCH/16), dim3(128), 0, stream,
                       y, T, E, Pi, out);
}